// Round 6
// baseline (329.671 us; speedup 1.0000x reference)
//
#include <hip/hip_runtime.h>

#define NT   512          // 8 waves; waves 6-7 handle staging tails in parallel
#define SPB  32           // samples per block -> 72 tiles of (16 samples x 1 window)
#define LSTR 386          // fp16 elements per sample row in LDS (193 dwords = 1 mod 32)
#define LPAD 64           // safety pad for invalid-k gathers
#define VSTR 34           // uint stride for vis/le1u pair-rows

// d_ws layout:
//   [0, 3072) uint2 : head weights as hi/lo f16-pair slots (V1 80x32, V2 16x32)
//   byte 24576      : lane-constant table [11][64] uint4 (fragments/biases/dofs)
#define WS_V2_OFF 2560
#define WS_SLOTS  3072

typedef __attribute__((ext_vector_type(4))) float     f32x4;
typedef __attribute__((ext_vector_type(8))) _Float16  f16x8;
typedef __attribute__((ext_vector_type(4))) _Float16  f16x4;

union U8 { f16x8 v; unsigned u[4]; uint4 q; };
union U4 { f16x4 v; unsigned u[2]; };

static __device__ inline unsigned pack_f16(float a, float b) {
    union { _Float16 h[2]; unsigned u; } c;
    c.h[0] = (_Float16)a; c.h[1] = (_Float16)b;
    return c.u;
}
static __device__ inline void split_pack(float a, float b, unsigned& hi, unsigned& lo) {
    const _Float16 ah = (_Float16)a, bh = (_Float16)b;
    hi = pack_f16((float)ah, (float)bh);
    lo = pack_f16(a - (float)ah, b - (float)bh);
}
static __device__ inline unsigned short to_f16u(float a) {
    union { _Float16 h; unsigned short u; } c;
    c.h = (_Float16)a;
    return c.u;
}
static __device__ inline float clamp1(float v) { return __builtin_amdgcn_fmed3f(v, -1.f, 1.f); }

// single-instruction packed f32->f16x2 (RTZ) for activations
static __device__ inline unsigned pkrtz(float a, float b) {
#if __has_builtin(__builtin_amdgcn_cvt_pkrtz)
    typedef __attribute__((ext_vector_type(2))) __fp16 fp16x2;
    union { fp16x2 v; unsigned u; } c;
    c.v = __builtin_amdgcn_cvt_pkrtz(a, b);
    return c.u;
#else
    unsigned r;
    asm("v_cvt_pkrtz_f16_f32 %0, %1, %2" : "=v"(r) : "v"(a), "v"(b));
    return r;
#endif
}

static __device__ inline f32x4 mfma32(f16x8 a, f16x8 b, f32x4 c) {
    return __builtin_amdgcn_mfma_f32_16x16x32_f16(a, b, c, 0, 0, 0);
}
static __device__ inline f32x4 mfma16(f16x4 a, f16x4 b, f32x4 c) {
#if __has_builtin(__builtin_amdgcn_mfma_f32_16x16x16f16)
    return __builtin_amdgcn_mfma_f32_16x16x16f16(a, b, c, 0, 0, 0);
#else
    f32x4 d;
    asm volatile("v_mfma_f32_16x16x16_f16 %0, %1, %2, %3\n\ts_nop 7\n\ts_nop 1"
                 : "=v"(d) : "v"(a), "v"(b), "v"(c));
    return d;
#endif
}

// ---- pre-kernel: pack head weights AND all per-lane constant fragments ----
// V1 pair 73 duplicates row 144's weights: it multiplies the f16 RESIDUAL of
// inp[:,384] (staged at vis pair 73), restoring full precision for the one
// unclamped (large-magnitude) vision element.
__global__ void lila_pack(const float* __restrict__ W1, const float* __restrict__ b1,
                          const float* __restrict__ W2, const float* __restrict__ b2,
                          const float* __restrict__ W3, const float* __restrict__ b3,
                          const float* __restrict__ V1, const float* __restrict__ V2,
                          uint2* __restrict__ ws)
{
    const int i = blockIdx.x * 256 + threadIdx.x;
    if (i < WS_SLOTS) {
        float a, b;
        if (i < WS_V2_OFF) {
            const int p = i >> 5, n = i & 31;
            a = (2 * p < 145) ? V1[(2 * p) * 32 + n]
                              : ((p == 73) ? V1[144 * 32 + n] : 0.f);
            b = (2 * p + 1 < 145) ? V1[(2 * p + 1) * 32 + n] : 0.f;
        } else {
            const int j = i - WS_V2_OFF, p = j >> 5, n = j & 31;
            a = V2[(2 * p)     * 32 + n];
            b = V2[(2 * p + 1) * 32 + n];
        }
        uint2 t;
        split_pack(a, b, t.x, t.y);
        ws[i] = t;
    } else if (i < WS_SLOTS + 64) {
        const int lid  = i - WS_SLOTS;
        const int quad = lid >> 4, c16 = lid & 15;
        uint4* lc = (uint4*)(ws + WS_SLOTS);
        // W1 fragments (hi/lo)
        for (int f = 0; f < 2; ++f) {
            unsigned hu[4], lu[4];
            for (int j2 = 0; j2 < 4; ++j2) {
                const int k0 = f * 32 + quad * 8 + 2 * j2;
                const float v0 = (k0     < 54 && c16 < 12) ? W1[k0 * 12 + c16]       : 0.f;
                const float v1 = (k0 + 1 < 54 && c16 < 12) ? W1[(k0 + 1) * 12 + c16] : 0.f;
                split_pack(v0, v1, hu[j2], lu[j2]);
            }
            lc[(0 + f) * 64 + lid] = make_uint4(hu[0], hu[1], hu[2], hu[3]);
            lc[(2 + f) * 64 + lid] = make_uint4(lu[0], lu[1], lu[2], lu[3]);
        }
        // W2/W3 fragments
        {
            unsigned h2[2], l2[2], h3[2], l3[2];
            for (int j2 = 0; j2 < 2; ++j2) {
                const int k0 = quad * 4 + 2 * j2;
                const float a0 = (k0     < 12 && c16 < 12) ? W2[k0 * 12 + c16]       : 0.f;
                const float a1 = (k0 + 1 < 12 && c16 < 12) ? W2[(k0 + 1) * 12 + c16] : 0.f;
                split_pack(a0, a1, h2[j2], l2[j2]);
                const float g0 = (k0     < 12 && c16 < 4) ? W3[k0 * 4 + c16]       : 0.f;
                const float g1 = (k0 + 1 < 12 && c16 < 4) ? W3[(k0 + 1) * 4 + c16] : 0.f;
                split_pack(g0, g1, h3[j2], l3[j2]);
            }
            lc[4 * 64 + lid] = make_uint4(h2[0], h2[1], l2[0], l2[1]);
            lc[5 * 64 + lid] = make_uint4(h3[0], h3[1], l3[0], l3[1]);
        }
        // biases
        {
            unsigned q1[4], q2[4], q3[4];
            for (int r = 0; r < 4; ++r) {
                const int c = quad * 4 + r;
                q1[r] = __float_as_uint((c < 12) ? b1[c] : 0.f);
                q2[r] = __float_as_uint((c < 12) ? b2[c] : 0.f);
                q3[r] = __float_as_uint((c < 4)  ? b3[c] : 0.f);
            }
            lc[6 * 64 + lid] = make_uint4(q1[0], q1[1], q1[2], q1[3]);
            lc[7 * 64 + lid] = make_uint4(q2[0], q2[1], q2[2], q2[3]);
            lc[8 * 64 + lid] = make_uint4(q3[0], q3[1], q3[2], q3[3]);
        }
        // gather offsets (invalid k point at finite data; weights are 0 there)
        {
            unsigned d[8];
            for (int p = 0; p < 8; ++p) {
                const int k = (p >> 2) * 32 + quad * 8 + 2 * (p & 3);
                d[p] = (unsigned)((k / 18) * 48 + (k % 18));
            }
            lc[9  * 64 + lid] = make_uint4(d[0], d[1], d[2], d[3]);
            lc[10 * 64 + lid] = make_uint4(d[4], d[5], d[6], d[7]);
        }
    }
}

__global__ __launch_bounds__(NT, 8)
void lila_fused(const float* __restrict__ inp,
                const float* __restrict__ c1, const float* __restrict__ c2,
                const float* __restrict__ V3, const float* __restrict__ c3,
                const uint2* __restrict__ wpk,
                float* __restrict__ out)
{
    // LDS: 24,832 + 10,880 = 35,712 B -> 4 blocks/CU x 8 waves = 32 waves/CU
    __shared__ __align__(16) unsigned short lbuf16[SPB * LSTR + LPAD]; // fp16 inputs
    __shared__ __align__(16) unsigned vis[80 * VSTR]; // vision hi-pairs [p][grp*16+rot]

    unsigned* le1u = (unsigned*)lbuf16;               // overlay: e1 hi-pairs (phases 2/3)

    const int tid  = threadIdx.x;
    const int lid  = tid & 63;
    const int wv   = tid >> 6;
    const int quad = lid >> 4;
    const int c16  = lid & 15;
    const int s0   = blockIdx.x * SPB;

    // ---- per-lane constants: 11 coalesced dwordx4 loads from ws (L2-hot) ----
    const uint4* lc = (const uint4*)(wpk + WS_SLOTS);
    U8 wa1h[2], wa1l[2];
    wa1h[0].q = lc[0 * 64 + lid];
    wa1h[1].q = lc[1 * 64 + lid];
    wa1l[0].q = lc[2 * 64 + lid];
    wa1l[1].q = lc[3 * 64 + lid];
    const uint4 t4 = lc[4 * 64 + lid], t5 = lc[5 * 64 + lid];
    U4 wa2h, wa2l, wa3h, wa3l;
    wa2h.u[0] = t4.x; wa2h.u[1] = t4.y; wa2l.u[0] = t4.z; wa2l.u[1] = t4.w;
    wa3h.u[0] = t5.x; wa3h.u[1] = t5.y; wa3l.u[0] = t5.z; wa3l.u[1] = t5.w;
    const uint4 t6 = lc[6 * 64 + lid], t7 = lc[7 * 64 + lid], t8 = lc[8 * 64 + lid];
    const f32x4 accb1 = {__uint_as_float(t6.x), __uint_as_float(t6.y),
                         __uint_as_float(t6.z), __uint_as_float(t6.w)};
    const f32x4 accb2 = {__uint_as_float(t7.x), __uint_as_float(t7.y),
                         __uint_as_float(t7.z), __uint_as_float(t7.w)};
    const f32x4 accb3 = {__uint_as_float(t8.x), __uint_as_float(t8.y),
                         __uint_as_float(t8.z), __uint_as_float(t8.w)};
    const uint4 t9 = lc[9 * 64 + lid], tA = lc[10 * 64 + lid];
    // per-lane gather bases: sample-lane row + k-offset (wave-uniform part added per tile)
    int vb[8];
    {
        const int d[8] = {(int)t9.x, (int)t9.y, (int)t9.z, (int)t9.w,
                          (int)tA.x, (int)tA.y, (int)tA.z, (int)tA.w};
        #pragma unroll
        for (int p = 0; p < 8; ++p) vb[p] = c16 * LSTR + d[p];
    }

    // ---- stage inputs -> LDS fp16 (waves 0-5); tails + vis pairs (waves 6-7) ----
    {
        const float* g = inp + (size_t)s0 * 385;
        if (tid < 384) {
            #pragma unroll 8
            for (int r = 0; r < SPB; ++r)
                lbuf16[r * LSTR + tid] = to_f16u(g[r * 385 + tid]);
        } else if (tid < 416) {              // cols 384-385 zero (col 384 unused by windows)
            const int r = tid - 384;
            *(unsigned*)&lbuf16[r * LSTR + 384] = 0u;
        } else if (tid < 448) {              // LPAD zeros + vis pairs 74-79 zero
            const int r = tid - 416;
            *(unsigned*)&lbuf16[SPB * LSTR + 2 * r] = 0u;
            #pragma unroll
            for (int pp = 74; pp < 80; ++pp)
                vis[pp * VSTR + (r & 16) + (((r & 15) + pp) & 15)] = 0u;
        } else if (tid < 480) {              // vis pair 72: f16(lastv)
            const int s = tid - 448;
            const float lv = g[s * 385 + 384];
            vis[72 * VSTR + (s & 16) + (((s & 15) + 72) & 15)] = pack_f16(lv, 0.f);
        } else {                             // vis pair 73: residual of lastv
            const int s = tid - 480;
            const float lv = g[s * 385 + 384];
            vis[73 * VSTR + (s & 16) + (((s & 15) + 73) & 15)] =
                pack_f16(lv - (float)(_Float16)lv, 0.f);
        }
    }
    __syncthreads();

    // ---- phase 1: tile t = (window w = t>>1, sample half = t&1); lane = sample ----
    // geometry is wave-uniform (SALU); lane stride LSTR = 193 dwords = 1 mod 32
    // -> the 16 sample-lanes hit 16 distinct banks: conflict-free gather.
    for (int t = wv; t < 2 * 36; t += NT / 64) {
        const int tt   = __builtin_amdgcn_readfirstlane(t);
        const int w    = tt >> 1;
        const int x    = w / 6;
        const int y    = w - 6 * x;
        const int sb   = (tt & 1) * 16;                       // sample-half base
        const int soff = sb * LSTR + x * 48 + y * 6;          // wave-uniform offset

        U8 bw[2];
        #pragma unroll
        for (int p = 0; p < 8; ++p)
            bw[p >> 2].u[p & 3] = *(const unsigned*)(&lbuf16[vb[p] + soff]);

        f32x4 acc = accb1;                        // bias rides in the accumulator
        acc = mfma32(wa1h[0].v, bw[0].v, acc);
        acc = mfma32(wa1h[1].v, bw[1].v, acc);
        acc = mfma32(wa1l[0].v, bw[0].v, acc);
        acc = mfma32(wa1l[1].v, bw[1].v, acc);

        U4 bb2;
        bb2.u[0] = pkrtz(clamp1(acc[0]), clamp1(acc[1]));
        bb2.u[1] = pkrtz(clamp1(acc[2]), clamp1(acc[3]));
        f32x4 d2 = accb2;
        d2 = mfma16(wa2h.v, bb2.v, d2);
        d2 = mfma16(wa2l.v, bb2.v, d2);

        U4 bb3;
        bb3.u[0] = pkrtz(clamp1(d2[0]), clamp1(d2[1]));
        bb3.u[1] = pkrtz(clamp1(d2[2]), clamp1(d2[3]));
        f32x4 d3 = accb3;
        d3 = mfma16(wa3h.v, bb3.v, d3);
        d3 = mfma16(wa3l.v, bb3.v, d3);

        if (lid < 16) {                           // quad0 holds sight channels 0..3
            const unsigned h01 = pkrtz(clamp1(d3[0]), clamp1(d3[1]));
            const unsigned h23 = pkrtz(clamp1(d3[2]), clamp1(d3[3]));
            const int p0 = 2 * w;                 // vision k = 4w..4w+3 -> pairs 2w, 2w+1
            vis[p0       * VSTR + sb + ((c16 + p0    ) & 15)] = h01;
            vis[(p0 + 1) * VSTR + sb + ((c16 + p0 + 1) & 15)] = h23;
        }
    }
    __syncthreads();

    // ---- phase 2: head layer 1 (145->32) as MFMA; 4 waves = 2 sample-halves x 2 col-halves ----
    if (wv < 4) {
        const int sh = wv >> 1, nt = wv & 1;
        const float4 c1v = *(const float4*)(c1 + nt * 16 + quad * 4);
        f32x4 acc = {c1v.x, c1v.y, c1v.z, c1v.w};
        #pragma unroll
        for (int kk = 0; kk < 5; ++kk) {
            U8 ah, al, bh;
            #pragma unroll
            for (int j2 = 0; j2 < 4; ++j2) {
                const int p = kk * 16 + quad * 4 + j2;
                const uint2 a = wpk[p * 32 + nt * 16 + c16];
                ah.u[j2] = a.x; al.u[j2] = a.y;
                bh.u[j2] = vis[p * VSTR + sh * 16 + ((c16 + p) & 15)];
            }
            acc = mfma32(al.v, bh.v, acc);        // (ah + al) * b, weight-exact
            acc = mfma32(ah.v, bh.v, acc);
        }
        const unsigned h01 = pkrtz(clamp1(acc[0]), clamp1(acc[1]));
        const unsigned h23 = pkrtz(clamp1(acc[2]), clamp1(acc[3]));
        const int p0 = nt * 8 + quad * 2;         // e1 channels 2p0.. -> pairs p0, p0+1
        le1u[p0       * VSTR + sh * 16 + ((c16 + p0    ) & 15)] = h01;
        le1u[(p0 + 1) * VSTR + sh * 16 + ((c16 + p0 + 1) & 15)] = h23;
    }
    __syncthreads();

    // ---- phase 3: head layer 2 (32->32) as MFMA + V3 dot + output; 2 waves ----
    if (wv < 2) {
        const int sh = wv;
        float part = 0.f;
        #pragma unroll
        for (int nt2 = 0; nt2 < 2; ++nt2) {
            U8 ah, al, bh;
            #pragma unroll
            for (int j2 = 0; j2 < 4; ++j2) {
                const int p = quad * 4 + j2;
                const uint2 a = wpk[WS_V2_OFF + p * 32 + nt2 * 16 + c16];
                ah.u[j2] = a.x; al.u[j2] = a.y;
                bh.u[j2] = le1u[p * VSTR + sh * 16 + ((c16 + p) & 15)];
            }
            const float4 c2v = *(const float4*)(c2 + nt2 * 16 + quad * 4);
            f32x4 d = {c2v.x, c2v.y, c2v.z, c2v.w};
            d = mfma32(al.v, bh.v, d);
            d = mfma32(ah.v, bh.v, d);
            const float4 v3v = *(const float4*)(V3 + nt2 * 16 + quad * 4);
            part += clamp1(d[0]) * v3v.x + clamp1(d[1]) * v3v.y
                  + clamp1(d[2]) * v3v.z + clamp1(d[3]) * v3v.w;
        }
        part += __shfl_xor(part, 16);             // sum over quads
        part += __shfl_xor(part, 32);
        if (lid < 16)
            out[s0 + sh * 16 + c16] = clamp1(part + c3[0]);
    }
}

extern "C" void kernel_launch(void* const* d_in, const int* in_sizes, int n_in,
                              void* d_out, int out_size, void* d_ws, size_t ws_size,
                              hipStream_t stream) {
    const float* inp = (const float*)d_in[0];
    const float* W1  = (const float*)d_in[1];
    const float* b1  = (const float*)d_in[2];
    const float* W2  = (const float*)d_in[3];
    const float* b2  = (const float*)d_in[4];
    const float* W3  = (const float*)d_in[5];
    const float* b3  = (const float*)d_in[6];
    const float* V1  = (const float*)d_in[7];
    const float* c1  = (const float*)d_in[8];
    const float* V2  = (const float*)d_in[9];
    const float* c2  = (const float*)d_in[10];
    const float* V3  = (const float*)d_in[11];
    const float* c3  = (const float*)d_in[12];
    float* out = (float*)d_out;

    uint2* wpk = (uint2*)d_ws;                 // 24,576 + 11,264 = 35,840 B used
    lila_pack<<<dim3((WS_SLOTS + 64 + 255) / 256), dim3(256), 0, stream>>>(
        W1, b1, W2, b2, W3, b3, V1, V2, wpk);

    const int Btot   = in_sizes[0] / 385;      // 131072
    const int blocks = Btot / SPB;             // 4096

    lila_fused<<<dim3(blocks), dim3(NT), 0, stream>>>(
        inp, c1, c2, V3, c3, wpk, out);
}

// Round 7
// 310.751 us; speedup vs baseline: 1.0609x; 1.0609x over previous
//
#include <hip/hip_runtime.h>

#define NT   384          // 6 waves
#define SPB  32           // samples per block -> 72 tiles of (16 samples x 1 window)
#define LSTR 386          // fp16 elements per sample row in LDS (193 dwords = 1 mod 32)
#define LPAD 64           // safety pad for invalid-k gathers
#define VSTR 34           // uint stride for vis/le1u pair-rows

// d_ws layout:
//   [0, 3072) uint2 : head weights as hi/lo f16-pair slots (V1 80x32, V2 16x32)
//   byte 24576      : lane-constant table [11][64] uint4 (fragments/biases/dofs)
#define WS_V2_OFF 2560
#define WS_SLOTS  3072

typedef __attribute__((ext_vector_type(4))) float     f32x4;
typedef __attribute__((ext_vector_type(8))) _Float16  f16x8;
typedef __attribute__((ext_vector_type(4))) _Float16  f16x4;

union U8 { f16x8 v; unsigned u[4]; uint4 q; };
union U4 { f16x4 v; unsigned u[2]; };

static __device__ inline unsigned pack_f16(float a, float b) {
    union { _Float16 h[2]; unsigned u; } c;
    c.h[0] = (_Float16)a; c.h[1] = (_Float16)b;
    return c.u;
}
static __device__ inline void split_pack(float a, float b, unsigned& hi, unsigned& lo) {
    const _Float16 ah = (_Float16)a, bh = (_Float16)b;
    hi = pack_f16((float)ah, (float)bh);
    lo = pack_f16(a - (float)ah, b - (float)bh);
}
static __device__ inline unsigned short to_f16u(float a) {
    union { _Float16 h; unsigned short u; } c;
    c.h = (_Float16)a;
    return c.u;
}
static __device__ inline float clamp1(float v) { return __builtin_amdgcn_fmed3f(v, -1.f, 1.f); }

// single-instruction packed f32->f16x2 (RTZ) for activations
static __device__ inline unsigned pkrtz(float a, float b) {
#if __has_builtin(__builtin_amdgcn_cvt_pkrtz)
    typedef __attribute__((ext_vector_type(2))) __fp16 fp16x2;
    union { fp16x2 v; unsigned u; } c;
    c.v = __builtin_amdgcn_cvt_pkrtz(a, b);
    return c.u;
#else
    unsigned r;
    asm("v_cvt_pkrtz_f16_f32 %0, %1, %2" : "=v"(r) : "v"(a), "v"(b));
    return r;
#endif
}

static __device__ inline f32x4 mfma32(f16x8 a, f16x8 b, f32x4 c) {
    return __builtin_amdgcn_mfma_f32_16x16x32_f16(a, b, c, 0, 0, 0);
}
static __device__ inline f32x4 mfma16(f16x4 a, f16x4 b, f32x4 c) {
#if __has_builtin(__builtin_amdgcn_mfma_f32_16x16x16f16)
    return __builtin_amdgcn_mfma_f32_16x16x16f16(a, b, c, 0, 0, 0);
#else
    f32x4 d;
    asm volatile("v_mfma_f32_16x16x16_f16 %0, %1, %2, %3\n\ts_nop 7\n\ts_nop 1"
                 : "=v"(d) : "v"(a), "v"(b), "v"(c));
    return d;
#endif
}

// ---- pre-kernel: pack head weights AND all per-lane constant fragments ----
// V1 pair 73 duplicates row 144's weights: it multiplies the f16 RESIDUAL of
// inp[:,384] (staged at vis pair 73), restoring full precision for the one
// unclamped (large-magnitude) vision element.
__global__ void lila_pack(const float* __restrict__ W1, const float* __restrict__ b1,
                          const float* __restrict__ W2, const float* __restrict__ b2,
                          const float* __restrict__ W3, const float* __restrict__ b3,
                          const float* __restrict__ V1, const float* __restrict__ V2,
                          uint2* __restrict__ ws)
{
    const int i = blockIdx.x * 256 + threadIdx.x;
    if (i < WS_SLOTS) {
        float a, b;
        if (i < WS_V2_OFF) {
            const int p = i >> 5, n = i & 31;
            a = (2 * p < 145) ? V1[(2 * p) * 32 + n]
                              : ((p == 73) ? V1[144 * 32 + n] : 0.f);
            b = (2 * p + 1 < 145) ? V1[(2 * p + 1) * 32 + n] : 0.f;
        } else {
            const int j = i - WS_V2_OFF, p = j >> 5, n = j & 31;
            a = V2[(2 * p)     * 32 + n];
            b = V2[(2 * p + 1) * 32 + n];
        }
        uint2 t;
        split_pack(a, b, t.x, t.y);
        ws[i] = t;
    } else if (i < WS_SLOTS + 64) {
        const int lid  = i - WS_SLOTS;
        const int quad = lid >> 4, c16 = lid & 15;
        uint4* lc = (uint4*)(ws + WS_SLOTS);
        // W1 fragments (hi/lo)
        for (int f = 0; f < 2; ++f) {
            unsigned hu[4], lu[4];
            for (int j2 = 0; j2 < 4; ++j2) {
                const int k0 = f * 32 + quad * 8 + 2 * j2;
                const float v0 = (k0     < 54 && c16 < 12) ? W1[k0 * 12 + c16]       : 0.f;
                const float v1 = (k0 + 1 < 54 && c16 < 12) ? W1[(k0 + 1) * 12 + c16] : 0.f;
                split_pack(v0, v1, hu[j2], lu[j2]);
            }
            lc[(0 + f) * 64 + lid] = make_uint4(hu[0], hu[1], hu[2], hu[3]);
            lc[(2 + f) * 64 + lid] = make_uint4(lu[0], lu[1], lu[2], lu[3]);
        }
        // W2/W3 fragments
        {
            unsigned h2[2], l2[2], h3[2], l3[2];
            for (int j2 = 0; j2 < 2; ++j2) {
                const int k0 = quad * 4 + 2 * j2;
                const float a0 = (k0     < 12 && c16 < 12) ? W2[k0 * 12 + c16]       : 0.f;
                const float a1 = (k0 + 1 < 12 && c16 < 12) ? W2[(k0 + 1) * 12 + c16] : 0.f;
                split_pack(a0, a1, h2[j2], l2[j2]);
                const float g0 = (k0     < 12 && c16 < 4) ? W3[k0 * 4 + c16]       : 0.f;
                const float g1 = (k0 + 1 < 12 && c16 < 4) ? W3[(k0 + 1) * 4 + c16] : 0.f;
                split_pack(g0, g1, h3[j2], l3[j2]);
            }
            lc[4 * 64 + lid] = make_uint4(h2[0], h2[1], l2[0], l2[1]);
            lc[5 * 64 + lid] = make_uint4(h3[0], h3[1], l3[0], l3[1]);
        }
        // biases
        {
            unsigned q1[4], q2[4], q3[4];
            for (int r = 0; r < 4; ++r) {
                const int c = quad * 4 + r;
                q1[r] = __float_as_uint((c < 12) ? b1[c] : 0.f);
                q2[r] = __float_as_uint((c < 12) ? b2[c] : 0.f);
                q3[r] = __float_as_uint((c < 4)  ? b3[c] : 0.f);
            }
            lc[6 * 64 + lid] = make_uint4(q1[0], q1[1], q1[2], q1[3]);
            lc[7 * 64 + lid] = make_uint4(q2[0], q2[1], q2[2], q2[3]);
            lc[8 * 64 + lid] = make_uint4(q3[0], q3[1], q3[2], q3[3]);
        }
        // gather offsets (invalid k point at finite data; weights are 0 there)
        {
            unsigned d[8];
            for (int p = 0; p < 8; ++p) {
                const int k = (p >> 2) * 32 + quad * 8 + 2 * (p & 3);
                d[p] = (unsigned)((k / 18) * 48 + (k % 18));
            }
            lc[9  * 64 + lid] = make_uint4(d[0], d[1], d[2], d[3]);
            lc[10 * 64 + lid] = make_uint4(d[4], d[5], d[6], d[7]);
        }
    }
}

__global__ __launch_bounds__(NT, 6)
void lila_fused(const float* __restrict__ inp,
                const float* __restrict__ c1, const float* __restrict__ c2,
                const float* __restrict__ V3, const float* __restrict__ c3,
                const uint2* __restrict__ wpk,
                float* __restrict__ out)
{
    // LDS: 24,832 + 10,880 = 35,712 B -> 4 blocks/CU (24 waves)
    __shared__ __align__(16) unsigned short lbuf16[SPB * LSTR + LPAD]; // fp16 inputs
    __shared__ __align__(16) unsigned vis[80 * VSTR]; // vision hi-pairs [p][grp*16+rot]

    unsigned* le1u = (unsigned*)lbuf16;               // overlay: e1 hi-pairs (phases 2/3)

    const int tid  = threadIdx.x;
    const int lid  = tid & 63;
    const int wv   = tid >> 6;
    const int quad = lid >> 4;
    const int c16  = lid & 15;
    const int s0   = blockIdx.x * SPB;

    // ---- per-lane constants: 11 coalesced dwordx4 loads from ws (L2-hot) ----
    const uint4* lc = (const uint4*)(wpk + WS_SLOTS);
    U8 wa1h[2], wa1l[2];
    wa1h[0].q = lc[0 * 64 + lid];
    wa1h[1].q = lc[1 * 64 + lid];
    wa1l[0].q = lc[2 * 64 + lid];
    wa1l[1].q = lc[3 * 64 + lid];
    const uint4 t4 = lc[4 * 64 + lid], t5 = lc[5 * 64 + lid];
    U4 wa2h, wa2l, wa3h, wa3l;
    wa2h.u[0] = t4.x; wa2h.u[1] = t4.y; wa2l.u[0] = t4.z; wa2l.u[1] = t4.w;
    wa3h.u[0] = t5.x; wa3h.u[1] = t5.y; wa3l.u[0] = t5.z; wa3l.u[1] = t5.w;
    const uint4 t6 = lc[6 * 64 + lid], t7 = lc[7 * 64 + lid], t8 = lc[8 * 64 + lid];
    const f32x4 accb1 = {__uint_as_float(t6.x), __uint_as_float(t6.y),
                         __uint_as_float(t6.z), __uint_as_float(t6.w)};
    const f32x4 accb2 = {__uint_as_float(t7.x), __uint_as_float(t7.y),
                         __uint_as_float(t7.z), __uint_as_float(t7.w)};
    const f32x4 accb3 = {__uint_as_float(t8.x), __uint_as_float(t8.y),
                         __uint_as_float(t8.z), __uint_as_float(t8.w)};
    const uint4 t9 = lc[9 * 64 + lid], tA = lc[10 * 64 + lid];
    // per-lane gather bases: sample-lane row + k-offset (wave-uniform part added per tile)
    int vb[8];
    {
        const int d[8] = {(int)t9.x, (int)t9.y, (int)t9.z, (int)t9.w,
                          (int)tA.x, (int)tA.y, (int)tA.z, (int)tA.w};
        #pragma unroll
        for (int p = 0; p < 8; ++p) vb[p] = c16 * LSTR + d[p];
    }

    // ---- stage inputs -> LDS fp16 (vectorized float4, RTN cvt); tails; vis 72..79 ----
    {
        const float* g = inp + (size_t)s0 * 385;
        const int seg = tid % 96;           // 96 float4 segs cover cols 0..383
        const int r0  = tid / 96;           // 4 rows per iteration
        #pragma unroll
        for (int i = 0; i < 8; ++i) {
            const int r = i * 4 + r0;
            const float4 v = *(const float4*)(g + r * 385 + seg * 4);
            unsigned* d = (unsigned*)&lbuf16[r * LSTR + seg * 4];
            d[0] = pack_f16(v.x, v.y);      // RTN per element (numerics unchanged)
            d[1] = pack_f16(v.z, v.w);
        }
        if (tid < 64)        *(unsigned*)&lbuf16[(tid >> 1) * LSTR + 384] = 0u; // cols 384/385
        else if (tid < 96) { // LPAD zeros
            const int r = tid - 64;
            *(unsigned*)&lbuf16[SPB * LSTR + 2 * r] = 0u;
        } else if (tid < 128) { // vis pairs 74..79 zero
            const int r = tid - 96;
            #pragma unroll
            for (int pp = 74; pp < 80; ++pp)
                vis[pp * VSTR + (r & 16) + (((r & 15) + pp) & 15)] = 0u;
        } else if (tid < 160) { // vis pair 72: f16(lastv)
            const int s = tid - 128;
            const float lv = g[s * 385 + 384];
            vis[72 * VSTR + (s & 16) + (((s & 15) + 72) & 15)] = pack_f16(lv, 0.f);
        } else if (tid < 192) { // vis pair 73: residual of lastv
            const int s = tid - 160;
            const float lv = g[s * 385 + 384];
            vis[73 * VSTR + (s & 16) + (((s & 15) + 73) & 15)] =
                pack_f16(lv - (float)(_Float16)lv, 0.f);
        }
    }
    __syncthreads();

    // ---- phase 1: tile t = (window w = t>>1, sample half = t&1); lane = sample ----
    // geometry is wave-uniform (SALU); lane stride LSTR = 193 dwords = 1 mod 32
    // -> the 16 sample-lanes hit 16 distinct banks: conflict-free gather.
    for (int t = wv; t < 2 * 36; t += NT / 64) {
        const int tt   = __builtin_amdgcn_readfirstlane(t);
        const int w    = tt >> 1;
        const int x    = w / 6;
        const int y    = w - 6 * x;
        const int sb   = (tt & 1) * 16;                       // sample-half base
        const int soff = sb * LSTR + x * 48 + y * 6;          // wave-uniform offset

        U8 bw[2];
        #pragma unroll
        for (int p = 0; p < 8; ++p)
            bw[p >> 2].u[p & 3] = *(const unsigned*)(&lbuf16[vb[p] + soff]);

        f32x4 acc = accb1;                        // bias rides in the accumulator
        acc = mfma32(wa1h[0].v, bw[0].v, acc);
        acc = mfma32(wa1h[1].v, bw[1].v, acc);
        acc = mfma32(wa1l[0].v, bw[0].v, acc);
        acc = mfma32(wa1l[1].v, bw[1].v, acc);

        U4 bb2;
        bb2.u[0] = pkrtz(clamp1(acc[0]), clamp1(acc[1]));
        bb2.u[1] = pkrtz(clamp1(acc[2]), clamp1(acc[3]));
        f32x4 d2 = accb2;
        d2 = mfma16(wa2h.v, bb2.v, d2);
        d2 = mfma16(wa2l.v, bb2.v, d2);

        U4 bb3;
        bb3.u[0] = pkrtz(clamp1(d2[0]), clamp1(d2[1]));
        bb3.u[1] = pkrtz(clamp1(d2[2]), clamp1(d2[3]));
        f32x4 d3 = accb3;
        d3 = mfma16(wa3h.v, bb3.v, d3);
        d3 = mfma16(wa3l.v, bb3.v, d3);

        if (lid < 16) {                           // quad0 holds sight channels 0..3
            const unsigned h01 = pkrtz(clamp1(d3[0]), clamp1(d3[1]));
            const unsigned h23 = pkrtz(clamp1(d3[2]), clamp1(d3[3]));
            const int p0 = 2 * w;                 // vision k = 4w..4w+3 -> pairs 2w, 2w+1
            vis[p0       * VSTR + sb + ((c16 + p0    ) & 15)] = h01;
            vis[(p0 + 1) * VSTR + sb + ((c16 + p0 + 1) & 15)] = h23;
        }
    }
    __syncthreads();

    // ---- phase 2: head layer 1 (145->32) as MFMA; 4 waves = 2 sample-halves x 2 col-halves ----
    if (wv < 4) {
        const int sh = wv >> 1, nt = wv & 1;
        const float4 c1v = *(const float4*)(c1 + nt * 16 + quad * 4);
        f32x4 acc = {c1v.x, c1v.y, c1v.z, c1v.w};
        #pragma unroll
        for (int kk = 0; kk < 5; ++kk) {
            U8 ah, al, bh;
            #pragma unroll
            for (int j2 = 0; j2 < 4; ++j2) {
                const int p = kk * 16 + quad * 4 + j2;
                const uint2 a = wpk[p * 32 + nt * 16 + c16];
                ah.u[j2] = a.x; al.u[j2] = a.y;
                bh.u[j2] = vis[p * VSTR + sh * 16 + ((c16 + p) & 15)];
            }
            acc = mfma32(al.v, bh.v, acc);        // (ah + al) * b, weight-exact
            acc = mfma32(ah.v, bh.v, acc);
        }
        const unsigned h01 = pkrtz(clamp1(acc[0]), clamp1(acc[1]));
        const unsigned h23 = pkrtz(clamp1(acc[2]), clamp1(acc[3]));
        const int p0 = nt * 8 + quad * 2;         // e1 channels 2p0.. -> pairs p0, p0+1
        le1u[p0       * VSTR + sh * 16 + ((c16 + p0    ) & 15)] = h01;
        le1u[(p0 + 1) * VSTR + sh * 16 + ((c16 + p0 + 1) & 15)] = h23;
    }
    __syncthreads();

    // ---- phase 3: head layer 2 (32->32) as MFMA + V3 dot + output; 2 waves ----
    if (wv < 2) {
        const int sh = wv;
        float part = 0.f;
        #pragma unroll
        for (int nt2 = 0; nt2 < 2; ++nt2) {
            U8 ah, al, bh;
            #pragma unroll
            for (int j2 = 0; j2 < 4; ++j2) {
                const int p = quad * 4 + j2;
                const uint2 a = wpk[WS_V2_OFF + p * 32 + nt2 * 16 + c16];
                ah.u[j2] = a.x; al.u[j2] = a.y;
                bh.u[j2] = le1u[p * VSTR + sh * 16 + ((c16 + p) & 15)];
            }
            const float4 c2v = *(const float4*)(c2 + nt2 * 16 + quad * 4);
            f32x4 d = {c2v.x, c2v.y, c2v.z, c2v.w};
            d = mfma32(al.v, bh.v, d);
            d = mfma32(ah.v, bh.v, d);
            const float4 v3v = *(const float4*)(V3 + nt2 * 16 + quad * 4);
            part += clamp1(d[0]) * v3v.x + clamp1(d[1]) * v3v.y
                  + clamp1(d[2]) * v3v.z + clamp1(d[3]) * v3v.w;
        }
        part += __shfl_xor(part, 16);             // sum over quads
        part += __shfl_xor(part, 32);
        if (lid < 16)
            out[s0 + sh * 16 + c16] = clamp1(part + c3[0]);
    }
}

extern "C" void kernel_launch(void* const* d_in, const int* in_sizes, int n_in,
                              void* d_out, int out_size, void* d_ws, size_t ws_size,
                              hipStream_t stream) {
    const float* inp = (const float*)d_in[0];
    const float* W1  = (const float*)d_in[1];
    const float* b1  = (const float*)d_in[2];
    const float* W2  = (const float*)d_in[3];
    const float* b2  = (const float*)d_in[4];
    const float* W3  = (const float*)d_in[5];
    const float* b3  = (const float*)d_in[6];
    const float* V1  = (const float*)d_in[7];
    const float* c1  = (const float*)d_in[8];
    const float* V2  = (const float*)d_in[9];
    const float* c2  = (const float*)d_in[10];
    const float* V3  = (const float*)d_in[11];
    const float* c3  = (const float*)d_in[12];
    float* out = (float*)d_out;

    uint2* wpk = (uint2*)d_ws;                 // 24,576 + 11,264 = 35,840 B used
    lila_pack<<<dim3((WS_SLOTS + 64 + 255) / 256), dim3(256), 0, stream>>>(
        W1, b1, W2, b2, W3, b3, V1, V2, wpk);

    const int Btot   = in_sizes[0] / 385;      // 131072
    const int blocks = Btot / SPB;             // 4096

    lila_fused<<<dim3(blocks), dim3(NT), 0, stream>>>(
        inp, c1, c2, V3, c3, wpk, out);
}

// Round 8
// 306.300 us; speedup vs baseline: 1.0763x; 1.0145x over previous
//
#include <hip/hip_runtime.h>

#define NT   384          // 6 waves
#define SPB  32           // samples per block -> 36 windows x 2 sample-halves
#define LSTR 386          // fp16 elements per sample row in LDS (193 dwords = 1 mod 32)
#define LPAD 64           // safety pad for invalid-k gathers
#define VSTR 34           // uint stride for vis/le1u pair-rows

// d_ws layout:
//   [0, 3072) uint2 : head weights as hi/lo f16-pair slots (V1 80x32, V2 16x32)
//   byte 24576      : lane-constant table [11][64] uint4 (fragments/biases/dofs)
#define WS_V2_OFF 2560
#define WS_SLOTS  3072

typedef __attribute__((ext_vector_type(4))) float     f32x4;
typedef __attribute__((ext_vector_type(8))) _Float16  f16x8;
typedef __attribute__((ext_vector_type(4))) _Float16  f16x4;

union U8 { f16x8 v; unsigned u[4]; uint4 q; };
union U4 { f16x4 v; unsigned u[2]; };

static __device__ inline unsigned pack_f16(float a, float b) {
    union { _Float16 h[2]; unsigned u; } c;
    c.h[0] = (_Float16)a; c.h[1] = (_Float16)b;
    return c.u;
}
static __device__ inline void split_pack(float a, float b, unsigned& hi, unsigned& lo) {
    const _Float16 ah = (_Float16)a, bh = (_Float16)b;
    hi = pack_f16((float)ah, (float)bh);
    lo = pack_f16(a - (float)ah, b - (float)bh);
}
static __device__ inline unsigned short to_f16u(float a) {
    union { _Float16 h; unsigned short u; } c;
    c.h = (_Float16)a;
    return c.u;
}
static __device__ inline float clamp1(float v) { return __builtin_amdgcn_fmed3f(v, -1.f, 1.f); }

// single-instruction packed f32->f16x2 (RTZ) for activations
static __device__ inline unsigned pkrtz(float a, float b) {
#if __has_builtin(__builtin_amdgcn_cvt_pkrtz)
    typedef __attribute__((ext_vector_type(2))) __fp16 fp16x2;
    union { fp16x2 v; unsigned u; } c;
    c.v = __builtin_amdgcn_cvt_pkrtz(a, b);
    return c.u;
#else
    unsigned r;
    asm("v_cvt_pkrtz_f16_f32 %0, %1, %2" : "=v"(r) : "v"(a), "v"(b));
    return r;
#endif
}

static __device__ inline f32x4 mfma32(f16x8 a, f16x8 b, f32x4 c) {
    return __builtin_amdgcn_mfma_f32_16x16x32_f16(a, b, c, 0, 0, 0);
}
static __device__ inline f32x4 mfma16(f16x4 a, f16x4 b, f32x4 c) {
#if __has_builtin(__builtin_amdgcn_mfma_f32_16x16x16f16)
    return __builtin_amdgcn_mfma_f32_16x16x16f16(a, b, c, 0, 0, 0);
#else
    f32x4 d;
    asm volatile("v_mfma_f32_16x16x16_f16 %0, %1, %2, %3\n\ts_nop 7\n\ts_nop 1"
                 : "=v"(d) : "v"(a), "v"(b), "v"(c));
    return d;
#endif
}

// ---- pre-kernel: pack head weights AND all per-lane constant fragments ----
// V1 pair 73 duplicates row 144's weights: it multiplies the f16 RESIDUAL of
// inp[:,384] (staged at vis pair 73), restoring full precision for the one
// unclamped (large-magnitude) vision element.
__global__ void lila_pack(const float* __restrict__ W1, const float* __restrict__ b1,
                          const float* __restrict__ W2, const float* __restrict__ b2,
                          const float* __restrict__ W3, const float* __restrict__ b3,
                          const float* __restrict__ V1, const float* __restrict__ V2,
                          uint2* __restrict__ ws)
{
    const int i = blockIdx.x * 256 + threadIdx.x;
    if (i < WS_SLOTS) {
        float a, b;
        if (i < WS_V2_OFF) {
            const int p = i >> 5, n = i & 31;
            a = (2 * p < 145) ? V1[(2 * p) * 32 + n]
                              : ((p == 73) ? V1[144 * 32 + n] : 0.f);
            b = (2 * p + 1 < 145) ? V1[(2 * p + 1) * 32 + n] : 0.f;
        } else {
            const int j = i - WS_V2_OFF, p = j >> 5, n = j & 31;
            a = V2[(2 * p)     * 32 + n];
            b = V2[(2 * p + 1) * 32 + n];
        }
        uint2 t;
        split_pack(a, b, t.x, t.y);
        ws[i] = t;
    } else if (i < WS_SLOTS + 64) {
        const int lid  = i - WS_SLOTS;
        const int quad = lid >> 4, c16 = lid & 15;
        uint4* lc = (uint4*)(ws + WS_SLOTS);
        // W1 fragments (hi/lo)
        for (int f = 0; f < 2; ++f) {
            unsigned hu[4], lu[4];
            for (int j2 = 0; j2 < 4; ++j2) {
                const int k0 = f * 32 + quad * 8 + 2 * j2;
                const float v0 = (k0     < 54 && c16 < 12) ? W1[k0 * 12 + c16]       : 0.f;
                const float v1 = (k0 + 1 < 54 && c16 < 12) ? W1[(k0 + 1) * 12 + c16] : 0.f;
                split_pack(v0, v1, hu[j2], lu[j2]);
            }
            lc[(0 + f) * 64 + lid] = make_uint4(hu[0], hu[1], hu[2], hu[3]);
            lc[(2 + f) * 64 + lid] = make_uint4(lu[0], lu[1], lu[2], lu[3]);
        }
        // W2/W3 fragments
        {
            unsigned h2[2], l2[2], h3[2], l3[2];
            for (int j2 = 0; j2 < 2; ++j2) {
                const int k0 = quad * 4 + 2 * j2;
                const float a0 = (k0     < 12 && c16 < 12) ? W2[k0 * 12 + c16]       : 0.f;
                const float a1 = (k0 + 1 < 12 && c16 < 12) ? W2[(k0 + 1) * 12 + c16] : 0.f;
                split_pack(a0, a1, h2[j2], l2[j2]);
                const float g0 = (k0     < 12 && c16 < 4) ? W3[k0 * 4 + c16]       : 0.f;
                const float g1 = (k0 + 1 < 12 && c16 < 4) ? W3[(k0 + 1) * 4 + c16] : 0.f;
                split_pack(g0, g1, h3[j2], l3[j2]);
            }
            lc[4 * 64 + lid] = make_uint4(h2[0], h2[1], l2[0], l2[1]);
            lc[5 * 64 + lid] = make_uint4(h3[0], h3[1], l3[0], l3[1]);
        }
        // biases
        {
            unsigned q1[4], q2[4], q3[4];
            for (int r = 0; r < 4; ++r) {
                const int c = quad * 4 + r;
                q1[r] = __float_as_uint((c < 12) ? b1[c] : 0.f);
                q2[r] = __float_as_uint((c < 12) ? b2[c] : 0.f);
                q3[r] = __float_as_uint((c < 4)  ? b3[c] : 0.f);
            }
            lc[6 * 64 + lid] = make_uint4(q1[0], q1[1], q1[2], q1[3]);
            lc[7 * 64 + lid] = make_uint4(q2[0], q2[1], q2[2], q2[3]);
            lc[8 * 64 + lid] = make_uint4(q3[0], q3[1], q3[2], q3[3]);
        }
        // gather offsets (invalid k point at finite data; weights are 0 there)
        {
            unsigned d[8];
            for (int p = 0; p < 8; ++p) {
                const int k = (p >> 2) * 32 + quad * 8 + 2 * (p & 3);
                d[p] = (unsigned)((k / 18) * 48 + (k % 18));
            }
            lc[9  * 64 + lid] = make_uint4(d[0], d[1], d[2], d[3]);
            lc[10 * 64 + lid] = make_uint4(d[4], d[5], d[6], d[7]);
        }
    }
}

__global__ __launch_bounds__(NT, 6)
void lila_fused(const float* __restrict__ inp,
                const float* __restrict__ c1, const float* __restrict__ c2,
                const float* __restrict__ V3, const float* __restrict__ c3,
                const uint2* __restrict__ wpk,
                float* __restrict__ out)
{
    // LDS: 24,832 + 10,880 = 35,712 B -> 4 blocks/CU (24 waves)
    __shared__ __align__(16) unsigned short lbuf16[SPB * LSTR + LPAD]; // fp16 inputs
    __shared__ __align__(16) unsigned vis[80 * VSTR]; // vision hi-pairs [p][grp*16+rot]

    unsigned* le1u = (unsigned*)lbuf16;               // overlay: e1 hi-pairs (phases 2/3)

    const int tid  = threadIdx.x;
    const int lid  = tid & 63;
    const int wv   = tid >> 6;
    const int quad = lid >> 4;
    const int c16  = lid & 15;
    const int s0   = blockIdx.x * SPB;

    // ---- per-lane constants: 11 coalesced dwordx4 loads from ws (L2-hot) ----
    const uint4* lc = (const uint4*)(wpk + WS_SLOTS);
    U8 wa1h[2], wa1l[2];
    wa1h[0].q = lc[0 * 64 + lid];
    wa1h[1].q = lc[1 * 64 + lid];
    wa1l[0].q = lc[2 * 64 + lid];
    wa1l[1].q = lc[3 * 64 + lid];
    const uint4 t4 = lc[4 * 64 + lid], t5 = lc[5 * 64 + lid];
    U4 wa2h, wa2l, wa3h, wa3l;
    wa2h.u[0] = t4.x; wa2h.u[1] = t4.y; wa2l.u[0] = t4.z; wa2l.u[1] = t4.w;
    wa3h.u[0] = t5.x; wa3h.u[1] = t5.y; wa3l.u[0] = t5.z; wa3l.u[1] = t5.w;
    const uint4 t6 = lc[6 * 64 + lid], t7 = lc[7 * 64 + lid], t8 = lc[8 * 64 + lid];
    const f32x4 accb1 = {__uint_as_float(t6.x), __uint_as_float(t6.y),
                         __uint_as_float(t6.z), __uint_as_float(t6.w)};
    const f32x4 accb2 = {__uint_as_float(t7.x), __uint_as_float(t7.y),
                         __uint_as_float(t7.z), __uint_as_float(t7.w)};
    const f32x4 accb3 = {__uint_as_float(t8.x), __uint_as_float(t8.y),
                         __uint_as_float(t8.z), __uint_as_float(t8.w)};
    const uint4 t9 = lc[9 * 64 + lid], tA = lc[10 * 64 + lid];
    // per-lane gather bases: sample-lane row + k-offset (wave-uniform part added per tile)
    int vb[8];
    {
        const int d[8] = {(int)t9.x, (int)t9.y, (int)t9.z, (int)t9.w,
                          (int)tA.x, (int)tA.y, (int)tA.z, (int)tA.w};
        #pragma unroll
        for (int p = 0; p < 8; ++p) vb[p] = c16 * LSTR + d[p];
    }

    // ---- stage inputs -> LDS fp16 (vectorized float4, RTN cvt); tails; vis 72..79 ----
    {
        const float* g = inp + (size_t)s0 * 385;
        const int seg = tid % 96;           // 96 float4 segs cover cols 0..383
        const int r0  = tid / 96;           // 4 rows per iteration
        #pragma unroll
        for (int i = 0; i < 8; ++i) {
            const int r = i * 4 + r0;
            const float4 v = *(const float4*)(g + r * 385 + seg * 4);
            unsigned* d = (unsigned*)&lbuf16[r * LSTR + seg * 4];
            d[0] = pack_f16(v.x, v.y);      // RTN per element (numerics unchanged)
            d[1] = pack_f16(v.z, v.w);
        }
        if (tid < 64)        *(unsigned*)&lbuf16[(tid >> 1) * LSTR + 384] = 0u; // cols 384/385
        else if (tid < 96) { // LPAD zeros
            const int r = tid - 64;
            *(unsigned*)&lbuf16[SPB * LSTR + 2 * r] = 0u;
        } else if (tid < 128) { // vis pairs 74..79 zero
            const int r = tid - 96;
            #pragma unroll
            for (int pp = 74; pp < 80; ++pp)
                vis[pp * VSTR + (r & 16) + (((r & 15) + pp) & 15)] = 0u;
        } else if (tid < 160) { // vis pair 72: f16(lastv)
            const int s = tid - 128;
            const float lv = g[s * 385 + 384];
            vis[72 * VSTR + (s & 16) + (((s & 15) + 72) & 15)] = pack_f16(lv, 0.f);
        } else if (tid < 192) { // vis pair 73: residual of lastv
            const int s = tid - 160;
            const float lv = g[s * 385 + 384];
            vis[73 * VSTR + (s & 16) + (((s & 15) + 73) & 15)] =
                pack_f16(lv - (float)(_Float16)lv, 0.f);
        }
    }
    __syncthreads();

    // ---- phase 1: per iteration, one window w = i*6+wv, BOTH sample halves ----
    // Two independent chains (A: samples 0-15, B: samples 16-31) interleave to
    // hide the gather->MFMA->pack dependency latency. Geometry is SALU-uniform;
    // lane stride LSTR = 193 dwords = 1 mod 32 -> conflict-free gather.
    for (int i = 0; i < 6; ++i) {
        const int w     = __builtin_amdgcn_readfirstlane(i * 6 + wv);
        const int x     = w / 6;
        const int y     = w - 6 * x;
        const int soffA = x * 48 + y * 6;               // sample half A (sb = 0)
        const int soffB = soffA + 16 * LSTR;            // sample half B (sb = 16)

        U8 bwA[2], bwB[2];
        #pragma unroll
        for (int p = 0; p < 8; ++p) {
            bwA[p >> 2].u[p & 3] = *(const unsigned*)(&lbuf16[vb[p] + soffA]);
            bwB[p >> 2].u[p & 3] = *(const unsigned*)(&lbuf16[vb[p] + soffB]);
        }

        f32x4 aA = mfma32(wa1h[0].v, bwA[0].v, accb1);
        f32x4 aB = mfma32(wa1h[0].v, bwB[0].v, accb1);
        aA = mfma32(wa1h[1].v, bwA[1].v, aA);
        aB = mfma32(wa1h[1].v, bwB[1].v, aB);
        aA = mfma32(wa1l[0].v, bwA[0].v, aA);
        aB = mfma32(wa1l[0].v, bwB[0].v, aB);
        aA = mfma32(wa1l[1].v, bwA[1].v, aA);
        aB = mfma32(wa1l[1].v, bwB[1].v, aB);

        U4 b2A, b2B;
        b2A.u[0] = pkrtz(clamp1(aA[0]), clamp1(aA[1]));
        b2B.u[0] = pkrtz(clamp1(aB[0]), clamp1(aB[1]));
        b2A.u[1] = pkrtz(clamp1(aA[2]), clamp1(aA[3]));
        b2B.u[1] = pkrtz(clamp1(aB[2]), clamp1(aB[3]));
        f32x4 d2A = mfma16(wa2h.v, b2A.v, accb2);
        f32x4 d2B = mfma16(wa2h.v, b2B.v, accb2);
        d2A = mfma16(wa2l.v, b2A.v, d2A);
        d2B = mfma16(wa2l.v, b2B.v, d2B);

        U4 b3A, b3B;
        b3A.u[0] = pkrtz(clamp1(d2A[0]), clamp1(d2A[1]));
        b3B.u[0] = pkrtz(clamp1(d2B[0]), clamp1(d2B[1]));
        b3A.u[1] = pkrtz(clamp1(d2A[2]), clamp1(d2A[3]));
        b3B.u[1] = pkrtz(clamp1(d2B[2]), clamp1(d2B[3]));
        f32x4 d3A = mfma16(wa3h.v, b3A.v, accb3);
        f32x4 d3B = mfma16(wa3h.v, b3B.v, accb3);
        d3A = mfma16(wa3l.v, b3A.v, d3A);
        d3B = mfma16(wa3l.v, b3B.v, d3B);

        if (lid < 16) {                           // quad0 holds sight channels 0..3
            const int p0 = 2 * w;                 // vision k = 4w..4w+3 -> pairs 2w, 2w+1
            const int rA0 = (c16 + p0) & 15, rA1 = (c16 + p0 + 1) & 15;
            vis[p0       * VSTR +      rA0] = pkrtz(clamp1(d3A[0]), clamp1(d3A[1]));
            vis[(p0 + 1) * VSTR +      rA1] = pkrtz(clamp1(d3A[2]), clamp1(d3A[3]));
            vis[p0       * VSTR + 16 + rA0] = pkrtz(clamp1(d3B[0]), clamp1(d3B[1]));
            vis[(p0 + 1) * VSTR + 16 + rA1] = pkrtz(clamp1(d3B[2]), clamp1(d3B[3]));
        }
    }
    __syncthreads();

    // ---- phase 2: head layer 1 (145->32) as MFMA; 4 waves = 2 sample-halves x 2 col-halves ----
    if (wv < 4) {
        const int sh = wv >> 1, nt = wv & 1;
        const float4 c1v = *(const float4*)(c1 + nt * 16 + quad * 4);
        f32x4 acc = {c1v.x, c1v.y, c1v.z, c1v.w};
        #pragma unroll
        for (int kk = 0; kk < 5; ++kk) {
            U8 ah, al, bh;
            #pragma unroll
            for (int j2 = 0; j2 < 4; ++j2) {
                const int p = kk * 16 + quad * 4 + j2;
                const uint2 a = wpk[p * 32 + nt * 16 + c16];
                ah.u[j2] = a.x; al.u[j2] = a.y;
                bh.u[j2] = vis[p * VSTR + sh * 16 + ((c16 + p) & 15)];
            }
            acc = mfma32(al.v, bh.v, acc);        // (ah + al) * b, weight-exact
            acc = mfma32(ah.v, bh.v, acc);
        }
        const unsigned h01 = pkrtz(clamp1(acc[0]), clamp1(acc[1]));
        const unsigned h23 = pkrtz(clamp1(acc[2]), clamp1(acc[3]));
        const int p0 = nt * 8 + quad * 2;         // e1 channels 2p0.. -> pairs p0, p0+1
        le1u[p0       * VSTR + sh * 16 + ((c16 + p0    ) & 15)] = h01;
        le1u[(p0 + 1) * VSTR + sh * 16 + ((c16 + p0 + 1) & 15)] = h23;
    }
    __syncthreads();

    // ---- phase 3: head layer 2 (32->32) as MFMA + V3 dot + output; 2 waves ----
    if (wv < 2) {
        const int sh = wv;
        float part = 0.f;
        #pragma unroll
        for (int nt2 = 0; nt2 < 2; ++nt2) {
            U8 ah, al, bh;
            #pragma unroll
            for (int j2 = 0; j2 < 4; ++j2) {
                const int p = quad * 4 + j2;
                const uint2 a = wpk[WS_V2_OFF + p * 32 + nt2 * 16 + c16];
                ah.u[j2] = a.x; al.u[j2] = a.y;
                bh.u[j2] = le1u[p * VSTR + sh * 16 + ((c16 + p) & 15)];
            }
            const float4 c2v = *(const float4*)(c2 + nt2 * 16 + quad * 4);
            f32x4 d = {c2v.x, c2v.y, c2v.z, c2v.w};
            d = mfma32(al.v, bh.v, d);
            d = mfma32(ah.v, bh.v, d);
            const float4 v3v = *(const float4*)(V3 + nt2 * 16 + quad * 4);
            part += clamp1(d[0]) * v3v.x + clamp1(d[1]) * v3v.y
                  + clamp1(d[2]) * v3v.z + clamp1(d[3]) * v3v.w;
        }
        part += __shfl_xor(part, 16);             // sum over quads
        part += __shfl_xor(part, 32);
        if (lid < 16)
            out[s0 + sh * 16 + c16] = clamp1(part + c3[0]);
    }
}

extern "C" void kernel_launch(void* const* d_in, const int* in_sizes, int n_in,
                              void* d_out, int out_size, void* d_ws, size_t ws_size,
                              hipStream_t stream) {
    const float* inp = (const float*)d_in[0];
    const float* W1  = (const float*)d_in[1];
    const float* b1  = (const float*)d_in[2];
    const float* W2  = (const float*)d_in[3];
    const float* b2  = (const float*)d_in[4];
    const float* W3  = (const float*)d_in[5];
    const float* b3  = (const float*)d_in[6];
    const float* V1  = (const float*)d_in[7];
    const float* c1  = (const float*)d_in[8];
    const float* V2  = (const float*)d_in[9];
    const float* c2  = (const float*)d_in[10];
    const float* V3  = (const float*)d_in[11];
    const float* c3  = (const float*)d_in[12];
    float* out = (float*)d_out;

    uint2* wpk = (uint2*)d_ws;                 // 24,576 + 11,264 = 35,840 B used
    lila_pack<<<dim3((WS_SLOTS + 64 + 255) / 256), dim3(256), 0, stream>>>(
        W1, b1, W2, b2, W3, b3, V1, V2, wpk);

    const int Btot   = in_sizes[0] / 385;      // 131072
    const int blocks = Btot / SPB;             // 4096

    lila_fused<<<dim3(blocks), dim3(NT), 0, stream>>>(
        inp, c1, c2, V3, c3, wpk, out);
}